// Round 1
// 2620.133 us; speedup vs baseline: 1.4760x; 1.4760x over previous
//
#include <hip/hip_runtime.h>

#define D_MODEL 768
#define D_INNER 1536
#define SEQ 1024
#define DT_RANK 48
#define D_STATE 16
#define VOCAB 50280

typedef __attribute__((ext_vector_type(8))) short short8;
typedef __attribute__((ext_vector_type(4))) float float4v;

static __device__ __forceinline__ unsigned short f2bf(float f) {
    unsigned u = __builtin_bit_cast(unsigned, f);
    u += 0x7fffu + ((u >> 16) & 1u);   // RNE
    return (unsigned short)(u >> 16);
}

// ---------------------------------------------------------------- embed
__global__ __launch_bounds__(256) void embed_kernel(
    const int* __restrict__ ids, const float* __restrict__ emb,
    float* __restrict__ h)
{
    int d = blockIdx.x * 256 + threadIdx.x;   // < 768
    int l = blockIdx.y;
    h[l * D_MODEL + d] = emb[(size_t)ids[l] * D_MODEL + d];
}

// ---------------------------------------------------------------- layernorm (768 cols)
__global__ __launch_bounds__(256) void ln_kernel(
    const float* __restrict__ in, const float* __restrict__ w,
    const float* __restrict__ b, float* __restrict__ out)
{
    int row = blockIdx.x, tid = threadIdx.x;
    const float* p = in + (size_t)row * D_MODEL;
    float x0 = p[tid], x1 = p[tid + 256], x2 = p[tid + 512];
    float s = x0 + x1 + x2;
    float s2 = x0 * x0 + x1 * x1 + x2 * x2;
    #pragma unroll
    for (int o = 1; o < 64; o <<= 1) {
        s  += __shfl_xor(s, o);
        s2 += __shfl_xor(s2, o);
    }
    __shared__ float rs[4], rs2[4], mv[2];
    int wv = tid >> 6, lane = tid & 63;
    if (lane == 0) { rs[wv] = s; rs2[wv] = s2; }
    __syncthreads();
    if (tid == 0) {
        float S = rs[0] + rs[1] + rs[2] + rs[3];
        float S2 = rs2[0] + rs2[1] + rs2[2] + rs2[3];
        float mu = S / (float)D_MODEL;
        float var = S2 / (float)D_MODEL - mu * mu;
        mv[0] = mu; mv[1] = rsqrtf(fmaxf(var, 0.f) + 1e-5f);
    }
    __syncthreads();
    float mu = mv[0], rstd = mv[1];
    float* q = out + (size_t)row * D_MODEL;
    q[tid]       = (x0 - mu) * rstd * w[tid]       + b[tid];
    q[tid + 256] = (x1 - mu) * rstd * w[tid + 256] + b[tid + 256];
    q[tid + 512] = (x2 - mu) * rstd * w[tid + 512] + b[tid + 512];
}

// ---------------------------------------------------------------- causal depthwise conv4 + silu
__global__ __launch_bounds__(256) void conv_silu_kernel(
    const float* __restrict__ xz, const float* __restrict__ cw,
    const float* __restrict__ cb, float* __restrict__ xc)
{
    int d = blockIdx.x * 256 + threadIdx.x;   // < 1536
    int l = blockIdx.y;
    float acc = cb[d];
    #pragma unroll
    for (int j = 0; j < 4; ++j) {
        int ll = l - 3 + j;
        if (ll >= 0)
            acc += xz[(size_t)ll * (2 * D_INNER) + d] * cw[d * 4 + j];
    }
    float sig = 1.f / (1.f + __expf(-acc));
    xc[(size_t)l * D_INNER + d] = acc * sig;
}

// ---------------------------------------------------------------- dt_proj: softplus(dt_in @ W^T + b)
__global__ __launch_bounds__(256) void dtproj_kernel(
    const float* __restrict__ xdbl, const float* __restrict__ w,
    const float* __restrict__ b, float* __restrict__ dtb)
{
    int l = blockIdx.y;
    int d = blockIdx.x * 256 + threadIdx.x;   // < 1536
    __shared__ float xr[DT_RANK];
    if (threadIdx.x < DT_RANK) xr[threadIdx.x] = xdbl[(size_t)l * 80 + threadIdx.x];
    __syncthreads();
    const float4v* wp = (const float4v*)(w + (size_t)d * DT_RANK);
    float acc = b[d];
    #pragma unroll
    for (int i = 0; i < DT_RANK / 4; ++i) {
        float4v ww = wp[i];
        #pragma unroll
        for (int j = 0; j < 4; ++j)
            acc += xr[i * 4 + j] * ww[j];
    }
    float sp = (acc > 20.f) ? acc : log1pf(__expf(acc));
    dtb[(size_t)l * D_INNER + d] = sp;
}

// ---------------------------------------------------------------- selective scan
// Block = 256 threads = 16 channels x 16 states, one block per 16 channels.
// Inputs staged per 64-step chunk into LDS via async global_load_lds,
// double-buffered so HBM latency hides under the chunk's compute.
#define SCAN_T 64
#define SCAN_NCK (SEQ / SCAN_T)

typedef const __attribute__((address_space(1))) void* gas_ptr;
typedef __attribute__((address_space(3))) void* las_ptr;

__global__ __launch_bounds__(256) void scan_kernel(
    const float* __restrict__ xc,    // (L, DI) conv+silu output
    const float* __restrict__ dtb,   // (L, DI) softplus(dt)
    const float* __restrict__ xdbl,  // (L, 80): [..,48:64]=B, [..,64:80]=C
    const float* __restrict__ xz,    // (L, 3072): z = cols 1536..
    const float* __restrict__ A_log, // (DI, 16)
    const float* __restrict__ Dw,    // (DI)
    float* __restrict__ y)           // (L, DI)
{
    __shared__ __align__(16) float sdt[2][SCAN_T][16];
    __shared__ __align__(16) float sx [2][SCAN_T][16];
    __shared__ __align__(16) float sB [2][SCAN_T][16];
    __shared__ __align__(16) float sC [2][SCAN_T][16];
    __shared__ __align__(16) float sz [2][SCAN_T][16];

    int tid = threadIdx.x;
    int n = tid & 15;          // state index
    int c = tid >> 4;          // channel within group
    int d0 = blockIdx.x * 16;
    int d = d0 + c;

    float Av = -__expf(A_log[d * D_STATE + n]);
    float Dv = Dw[d];
    float h = 0.f;

    // staging addressing: thread t moves one float4; LDS dest = tid*16 bytes
    int lrow = tid >> 2;          // 0..63 : l within chunk
    int c4   = (tid & 3) * 4;     // 0,4,8,12 : column within the 16-wide row

    float* ldt = &sdt[0][lrow][c4];
    float* lx  = &sx [0][lrow][c4];
    float* lB  = &sB [0][lrow][c4];
    float* lC  = &sC [0][lrow][c4];
    float* lz  = &sz [0][lrow][c4];
    const int bufstride = SCAN_T * 16;   // floats per buffer

    // prologue: stage chunk 0 into buffer 0
    {
        size_t l0 = 0;
        const float* gdt = dtb  + (l0 + lrow) * D_INNER + d0 + c4;
        const float* gx  = xc   + (l0 + lrow) * D_INNER + d0 + c4;
        const float* gB  = xdbl + (l0 + lrow) * 80 + DT_RANK + c4;
        const float* gC  = xdbl + (l0 + lrow) * 80 + DT_RANK + D_STATE + c4;
        const float* gz  = xz   + (l0 + lrow) * (2 * D_INNER) + D_INNER + d0 + c4;
        __builtin_amdgcn_global_load_lds((gas_ptr)gdt, (las_ptr)ldt, 16, 0, 0);
        __builtin_amdgcn_global_load_lds((gas_ptr)gx,  (las_ptr)lx,  16, 0, 0);
        __builtin_amdgcn_global_load_lds((gas_ptr)gB,  (las_ptr)lB,  16, 0, 0);
        __builtin_amdgcn_global_load_lds((gas_ptr)gC,  (las_ptr)lC,  16, 0, 0);
        __builtin_amdgcn_global_load_lds((gas_ptr)gz,  (las_ptr)lz,  16, 0, 0);
    }
    asm volatile("s_waitcnt vmcnt(0)" ::: "memory");
    __syncthreads();

    int cur = 0;
    for (int ck = 0; ck < SCAN_NCK; ++ck) {
        // issue async stage of next chunk into the other buffer
        if (ck + 1 < SCAN_NCK) {
            size_t l0 = (size_t)(ck + 1) * SCAN_T;
            int nb = (cur ^ 1) * bufstride;
            const float* gdt = dtb  + (l0 + lrow) * D_INNER + d0 + c4;
            const float* gx  = xc   + (l0 + lrow) * D_INNER + d0 + c4;
            const float* gB  = xdbl + (l0 + lrow) * 80 + DT_RANK + c4;
            const float* gC  = xdbl + (l0 + lrow) * 80 + DT_RANK + D_STATE + c4;
            const float* gz  = xz   + (l0 + lrow) * (2 * D_INNER) + D_INNER + d0 + c4;
            __builtin_amdgcn_global_load_lds((gas_ptr)gdt, (las_ptr)(ldt + nb), 16, 0, 0);
            __builtin_amdgcn_global_load_lds((gas_ptr)gx,  (las_ptr)(lx  + nb), 16, 0, 0);
            __builtin_amdgcn_global_load_lds((gas_ptr)gB,  (las_ptr)(lB  + nb), 16, 0, 0);
            __builtin_amdgcn_global_load_lds((gas_ptr)gC,  (las_ptr)(lC  + nb), 16, 0, 0);
            __builtin_amdgcn_global_load_lds((gas_ptr)gz,  (las_ptr)(lz  + nb), 16, 0, 0);
        }

        // compute this chunk out of LDS
        size_t lbase = (size_t)ck * SCAN_T;
        #pragma unroll 8
        for (int l = 0; l < SCAN_T; ++l) {
            float dt = sdt[cur][l][c];
            float xv = sx [cur][l][c];
            float Bv = sB [cur][l][n];
            float Cv = sC [cur][l][n];
            float dA = __expf(dt * Av);
            h = dA * h + (dt * xv) * Bv;
            float p = h * Cv;
            p += __shfl_xor(p, 1);
            p += __shfl_xor(p, 2);
            p += __shfl_xor(p, 4);
            p += __shfl_xor(p, 8);
            if (n == 0) {
                float zv = sz[cur][l][c];
                float sig = 1.f / (1.f + __expf(-zv));
                y[(lbase + l) * D_INNER + d] = (p + xv * Dv) * (zv * sig);
            }
        }

        // barrier drains vmcnt (next chunk landed) and retires LDS reads
        asm volatile("s_waitcnt vmcnt(0)" ::: "memory");
        __syncthreads();
        cur ^= 1;
    }
}

// ---------------------------------------------------------------- GEMM  C = A(MxK,f32) * B(NxK,f32)^T, bf16 MFMA compute
// Requires M%128==0, K%32==0. 128x128 tile, 4 waves, 4x4 of 16x16x32 bf16 MFMA.
#define BM 128
#define BN 128
#define BK 32

enum { MODE_PLAIN = 0, MODE_ADD = 1 };

template <int MODE>
__global__ __launch_bounds__(256) void gemm_bt(
    const float* __restrict__ A, const float* __restrict__ B,
    float* Cout, int M, int N, int K, int lda,
    const float* addend)
{
    __shared__ unsigned short As[BM][BK + 8];
    __shared__ unsigned short Bs[BN][BK + 8];

    int tid = threadIdx.x;
    int lane = tid & 63, wv = tid >> 6;
    int wm = (wv >> 1) * 64, wn = (wv & 1) * 64;
    int lm = lane & 15, quad = lane >> 4;
    int m0 = blockIdx.x * BM, n0 = blockIdx.y * BN;

    int r = tid >> 1;            // staging row 0..127
    int ch = (tid & 1) * 16;     // staging col offset 0/16

    float4v acc[4][4] = {};

    for (int k0 = 0; k0 < K; k0 += BK) {
        // ---- stage A (f32 -> bf16), always in-bounds: M%128==0, K%32==0
        {
            const float4v* ap4 = (const float4v*)(A + (size_t)(m0 + r) * lda + k0 + ch);
            float4v f0 = ap4[0], f1 = ap4[1], f2 = ap4[2], f3 = ap4[3];
            short8 t0, t1;
            #pragma unroll
            for (int j = 0; j < 4; ++j) {
                t0[j]     = (short)f2bf(f0[j]);
                t0[j + 4] = (short)f2bf(f1[j]);
                t1[j]     = (short)f2bf(f2[j]);
                t1[j + 4] = (short)f2bf(f3[j]);
            }
            *(short8*)&As[r][ch]     = t0;
            *(short8*)&As[r][ch + 8] = t1;
        }
        // ---- stage B (f32 -> bf16), row guard only
        {
            short8 u0, u1;
            if ((n0 + r) < N) {
                const float4v* bp4 = (const float4v*)(B + (size_t)(n0 + r) * K + k0 + ch);
                float4v g0 = bp4[0], g1 = bp4[1], g2 = bp4[2], g3 = bp4[3];
                #pragma unroll
                for (int j = 0; j < 4; ++j) {
                    u0[j]     = (short)f2bf(g0[j]);
                    u0[j + 4] = (short)f2bf(g1[j]);
                    u1[j]     = (short)f2bf(g2[j]);
                    u1[j + 4] = (short)f2bf(g3[j]);
                }
            } else {
                u0 = (short8)(short)0;
                u1 = (short8)(short)0;
            }
            *(short8*)&Bs[r][ch]     = u0;
            *(short8*)&Bs[r][ch + 8] = u1;
        }
        __syncthreads();

        short8 af[4], bfr[4];
        #pragma unroll
        for (int i = 0; i < 4; ++i)
            af[i] = *(const short8*)&As[wm + i * 16 + lm][quad * 8];
        #pragma unroll
        for (int i = 0; i < 4; ++i)
            bfr[i] = *(const short8*)&Bs[wn + i * 16 + lm][quad * 8];

        #pragma unroll
        for (int mi = 0; mi < 4; ++mi)
            #pragma unroll
            for (int ni = 0; ni < 4; ++ni)
                acc[mi][ni] = __builtin_amdgcn_mfma_f32_16x16x32_bf16(
                    af[mi], bfr[ni], acc[mi][ni], 0, 0, 0);

        __syncthreads();
    }

    // ---- epilogue: C row = quad*4+e, col = lm  (verified C/D layout)
    #pragma unroll
    for (int mi = 0; mi < 4; ++mi) {
        #pragma unroll
        for (int ni = 0; ni < 4; ++ni) {
            int m = m0 + wm + mi * 16 + quad * 4;
            int n = n0 + wn + ni * 16 + lm;
            if (n >= N) continue;
            #pragma unroll
            for (int e = 0; e < 4; ++e) {
                float v = acc[mi][ni][e];
                size_t off = (size_t)(m + e) * N + n;
                if (MODE == MODE_PLAIN) {
                    Cout[off] = v;
                } else {
                    Cout[off] = v + addend[off];
                }
            }
        }
    }
}

// ---------------------------------------------------------------- launch
extern "C" void kernel_launch(void* const* d_in, const int* in_sizes, int n_in,
                              void* d_out, int out_size, void* d_ws, size_t ws_size,
                              hipStream_t stream)
{
    const int*   ids   = (const int*)d_in[0];
    const float* emb   = (const float*)d_in[1];
    const float* ln_w  = (const float*)d_in[2];
    const float* ln_b  = (const float*)d_in[3];
    const float* inw   = (const float*)d_in[4];
    const float* cw    = (const float*)d_in[5];
    const float* cb    = (const float*)d_in[6];
    const float* xpw   = (const float*)d_in[7];
    const float* dtpw  = (const float*)d_in[8];
    const float* dtpb  = (const float*)d_in[9];
    const float* alog  = (const float*)d_in[10];
    const float* Dw    = (const float*)d_in[11];
    const float* outw  = (const float*)d_in[12];
    const float* lnfw  = (const float*)d_in[13];
    const float* lnfb  = (const float*)d_in[14];

    float* ws    = (float*)d_ws;
    float* ha    = ws;                           // 1024*768
    float* hb    = ha    + SEQ * D_MODEL;        // 1024*768
    float* hn    = hb    + SEQ * D_MODEL;        // 1024*768
    float* xz    = hn    + SEQ * D_MODEL;        // 1024*3072
    float* xconv = xz    + SEQ * 2 * D_INNER;    // 1024*1536
    float* xdbl  = xconv + SEQ * D_INNER;        // 1024*80
    float* dtb   = xdbl  + SEQ * 80;             // 1024*1536
    float* y     = dtb   + SEQ * D_INNER;        // 1024*1536

    embed_kernel<<<dim3(3, SEQ), 256, 0, stream>>>(ids, emb, ha);

    float* hcur = ha;
    float* hnxt = hb;
    for (int i = 0; i < 4; ++i) {
        ln_kernel<<<SEQ, 256, 0, stream>>>(hcur, ln_w + i * D_MODEL, ln_b + i * D_MODEL, hn);

        gemm_bt<MODE_PLAIN><<<dim3(8, 24), 256, 0, stream>>>(
            hn, inw + (size_t)i * 2 * D_INNER * D_MODEL, xz,
            SEQ, 2 * D_INNER, D_MODEL, D_MODEL, nullptr);

        conv_silu_kernel<<<dim3(6, SEQ), 256, 0, stream>>>(
            xz, cw + (size_t)i * D_INNER * 4, cb + (size_t)i * D_INNER, xconv);

        gemm_bt<MODE_PLAIN><<<dim3(8, 1), 256, 0, stream>>>(
            xconv, xpw + (size_t)i * 80 * D_INNER, xdbl,
            SEQ, 80, D_INNER, D_INNER, nullptr);

        dtproj_kernel<<<dim3(6, SEQ), 256, 0, stream>>>(
            xdbl, dtpw + (size_t)i * D_INNER * DT_RANK, dtpb + (size_t)i * D_INNER, dtb);

        scan_kernel<<<D_INNER / 16, 256, 0, stream>>>(
            xconv, dtb, xdbl, xz,
            alog + (size_t)i * D_INNER * D_STATE, Dw + (size_t)i * D_INNER, y);

        gemm_bt<MODE_ADD><<<dim3(8, 6), 256, 0, stream>>>(
            y, outw + (size_t)i * D_MODEL * D_INNER, hnxt,
            SEQ, D_MODEL, D_INNER, D_INNER, hcur);

        float* t = hcur; hcur = hnxt; hnxt = t;
    }

    ln_kernel<<<SEQ, 256, 0, stream>>>(hcur, lnfw, lnfb, hn);

    gemm_bt<MODE_PLAIN><<<dim3(8, (VOCAB + BN - 1) / BN), 256, 0, stream>>>(
        hn, emb, (float*)d_out, SEQ, VOCAB, D_MODEL, D_MODEL, nullptr);
}

// Round 3
// 2181.676 us; speedup vs baseline: 1.7726x; 1.2010x over previous
//
#include <hip/hip_runtime.h>

#define D_MODEL 768
#define D_INNER 1536
#define SEQ 1024
#define DT_RANK 48
#define D_STATE 16
#define VOCAB 50280

typedef __attribute__((ext_vector_type(8))) short short8;
typedef __attribute__((ext_vector_type(4))) float float4v;

static __device__ __forceinline__ unsigned short f2bf(float f) {
    unsigned u = __builtin_bit_cast(unsigned, f);
    u += 0x7fffu + ((u >> 16) & 1u);   // RNE
    return (unsigned short)(u >> 16);
}

// DPP row-reduce helper: p += lane(i-K) within the 16-lane row (invalid -> +0).
// After shr:1,2,4,8 lane 15 of each row holds the row sum.
template <int CTRL>
static __device__ __forceinline__ float dpp_row_add(float v) {
    int s = __builtin_amdgcn_update_dpp(
        0, __builtin_bit_cast(int, v), CTRL, 0xF, 0xF, false);
    return v + __builtin_bit_cast(float, s);
}

// ---------------------------------------------------------------- embed
__global__ __launch_bounds__(256) void embed_kernel(
    const int* __restrict__ ids, const float* __restrict__ emb,
    float* __restrict__ h)
{
    int d = blockIdx.x * 256 + threadIdx.x;   // < 768
    int l = blockIdx.y;
    h[l * D_MODEL + d] = emb[(size_t)ids[l] * D_MODEL + d];
}

// ---------------------------------------------------------------- layernorm (768 cols)
__global__ __launch_bounds__(256) void ln_kernel(
    const float* __restrict__ in, const float* __restrict__ w,
    const float* __restrict__ b, float* __restrict__ out)
{
    int row = blockIdx.x, tid = threadIdx.x;
    const float* p = in + (size_t)row * D_MODEL;
    float x0 = p[tid], x1 = p[tid + 256], x2 = p[tid + 512];
    float s = x0 + x1 + x2;
    float s2 = x0 * x0 + x1 * x1 + x2 * x2;
    #pragma unroll
    for (int o = 1; o < 64; o <<= 1) {
        s  += __shfl_xor(s, o);
        s2 += __shfl_xor(s2, o);
    }
    __shared__ float rs[4], rs2[4], mv[2];
    int wv = tid >> 6, lane = tid & 63;
    if (lane == 0) { rs[wv] = s; rs2[wv] = s2; }
    __syncthreads();
    if (tid == 0) {
        float S = rs[0] + rs[1] + rs[2] + rs[3];
        float S2 = rs2[0] + rs2[1] + rs2[2] + rs2[3];
        float mu = S / (float)D_MODEL;
        float var = S2 / (float)D_MODEL - mu * mu;
        mv[0] = mu; mv[1] = rsqrtf(fmaxf(var, 0.f) + 1e-5f);
    }
    __syncthreads();
    float mu = mv[0], rstd = mv[1];
    float* q = out + (size_t)row * D_MODEL;
    q[tid]       = (x0 - mu) * rstd * w[tid]       + b[tid];
    q[tid + 256] = (x1 - mu) * rstd * w[tid + 256] + b[tid + 256];
    q[tid + 512] = (x2 - mu) * rstd * w[tid + 512] + b[tid + 512];
}

// ---------------------------------------------------------------- causal depthwise conv4 + silu
__global__ __launch_bounds__(256) void conv_silu_kernel(
    const float* __restrict__ xz, const float* __restrict__ cw,
    const float* __restrict__ cb, float* __restrict__ xc)
{
    int d = blockIdx.x * 256 + threadIdx.x;   // < 1536
    int l = blockIdx.y;
    float acc = cb[d];
    #pragma unroll
    for (int j = 0; j < 4; ++j) {
        int ll = l - 3 + j;
        if (ll >= 0)
            acc += xz[(size_t)ll * (2 * D_INNER) + d] * cw[d * 4 + j];
    }
    float sig = 1.f / (1.f + __expf(-acc));
    xc[(size_t)l * D_INNER + d] = acc * sig;
}

// ---------------------------------------------------------------- dt_proj: softplus(dt_in @ W^T + b)
__global__ __launch_bounds__(256) void dtproj_kernel(
    const float* __restrict__ xdbl, const float* __restrict__ w,
    const float* __restrict__ b, float* __restrict__ dtb)
{
    int l = blockIdx.y;
    int d = blockIdx.x * 256 + threadIdx.x;   // < 1536
    __shared__ float xr[DT_RANK];
    if (threadIdx.x < DT_RANK) xr[threadIdx.x] = xdbl[(size_t)l * 80 + threadIdx.x];
    __syncthreads();
    const float4v* wp = (const float4v*)(w + (size_t)d * DT_RANK);
    float acc = b[d];
    #pragma unroll
    for (int i = 0; i < DT_RANK / 4; ++i) {
        float4v ww = wp[i];
        #pragma unroll
        for (int j = 0; j < 4; ++j)
            acc += xr[i * 4 + j] * ww[j];
    }
    float sp = (acc > 20.f) ? acc : log1pf(__expf(acc));
    dtb[(size_t)l * D_INNER + d] = sp;
}

// ---------------------------------------------------------------- selective scan
// Block = 256 threads = 16 channels x 16 states, one block per 16 channels.
// Inputs staged per 64-step chunk into LDS via async global_load_lds (double
// buffered). Cross-state reduce is 4 DPP row_shr adds (no LDS-pipe shfl).
#define SCAN_T 64
#define SCAN_NCK (SEQ / SCAN_T)

typedef const __attribute__((address_space(1))) void* gas_ptr;
typedef __attribute__((address_space(3))) void* las_ptr;

__global__ __launch_bounds__(256) void scan_kernel(
    const float* __restrict__ xc,    // (L, DI) conv+silu output
    const float* __restrict__ dtb,   // (L, DI) softplus(dt)
    const float* __restrict__ xdbl,  // (L, 80): [..,48:64]=B, [..,64:80]=C
    const float* __restrict__ xz,    // (L, 3072): z = cols 1536..
    const float* __restrict__ A_log, // (DI, 16)
    const float* __restrict__ Dw,    // (DI)
    float* __restrict__ y)           // (L, DI)
{
    __shared__ __align__(16) float sdt[2][SCAN_T][16];
    __shared__ __align__(16) float sx [2][SCAN_T][16];
    __shared__ __align__(16) float sB [2][SCAN_T][16];
    __shared__ __align__(16) float sC [2][SCAN_T][16];
    __shared__ __align__(16) float sz [2][SCAN_T][16];

    int tid = threadIdx.x;
    int n = tid & 15;          // state index
    int c = tid >> 4;          // channel within group
    int d0 = blockIdx.x * 16;
    int d = d0 + c;

    float Av = -__expf(A_log[d * D_STATE + n]);
    float Dv = Dw[d];
    float h = 0.f;

    // staging addressing: thread t moves one float4; LDS dest = tid*16 bytes
    int lrow = tid >> 2;          // 0..63 : l within chunk
    int c4   = (tid & 3) * 4;     // 0,4,8,12 : column within the 16-wide row

    float* ldt = &sdt[0][lrow][c4];
    float* lx  = &sx [0][lrow][c4];
    float* lB  = &sB [0][lrow][c4];
    float* lC  = &sC [0][lrow][c4];
    float* lz  = &sz [0][lrow][c4];
    const int bufstride = SCAN_T * 16;   // floats per buffer

    // prologue: stage chunk 0 into buffer 0
    {
        size_t l0 = 0;
        const float* gdt = dtb  + (l0 + lrow) * D_INNER + d0 + c4;
        const float* gx  = xc   + (l0 + lrow) * D_INNER + d0 + c4;
        const float* gB  = xdbl + (l0 + lrow) * 80 + DT_RANK + c4;
        const float* gC  = xdbl + (l0 + lrow) * 80 + DT_RANK + D_STATE + c4;
        const float* gz  = xz   + (l0 + lrow) * (2 * D_INNER) + D_INNER + d0 + c4;
        __builtin_amdgcn_global_load_lds((gas_ptr)gdt, (las_ptr)ldt, 16, 0, 0);
        __builtin_amdgcn_global_load_lds((gas_ptr)gx,  (las_ptr)lx,  16, 0, 0);
        __builtin_amdgcn_global_load_lds((gas_ptr)gB,  (las_ptr)lB,  16, 0, 0);
        __builtin_amdgcn_global_load_lds((gas_ptr)gC,  (las_ptr)lC,  16, 0, 0);
        __builtin_amdgcn_global_load_lds((gas_ptr)gz,  (las_ptr)lz,  16, 0, 0);
    }
    asm volatile("s_waitcnt vmcnt(0)" ::: "memory");
    __syncthreads();

    int cur = 0;
    for (int ck = 0; ck < SCAN_NCK; ++ck) {
        // issue async stage of next chunk into the other buffer
        if (ck + 1 < SCAN_NCK) {
            size_t l0 = (size_t)(ck + 1) * SCAN_T;
            int nb = (cur ^ 1) * bufstride;
            const float* gdt = dtb  + (l0 + lrow) * D_INNER + d0 + c4;
            const float* gx  = xc   + (l0 + lrow) * D_INNER + d0 + c4;
            const float* gB  = xdbl + (l0 + lrow) * 80 + DT_RANK + c4;
            const float* gC  = xdbl + (l0 + lrow) * 80 + DT_RANK + D_STATE + c4;
            const float* gz  = xz   + (l0 + lrow) * (2 * D_INNER) + D_INNER + d0 + c4;
            __builtin_amdgcn_global_load_lds((gas_ptr)gdt, (las_ptr)(ldt + nb), 16, 0, 0);
            __builtin_amdgcn_global_load_lds((gas_ptr)gx,  (las_ptr)(lx  + nb), 16, 0, 0);
            __builtin_amdgcn_global_load_lds((gas_ptr)gB,  (las_ptr)(lB  + nb), 16, 0, 0);
            __builtin_amdgcn_global_load_lds((gas_ptr)gC,  (las_ptr)(lC  + nb), 16, 0, 0);
            __builtin_amdgcn_global_load_lds((gas_ptr)gz,  (las_ptr)(lz  + nb), 16, 0, 0);
        }

        // compute this chunk out of LDS
        size_t lbase = (size_t)ck * SCAN_T;
        #pragma unroll 16
        for (int l = 0; l < SCAN_T; ++l) {
            float dt = sdt[cur][l][c];
            float xv = sx [cur][l][c];
            float Bv = sB [cur][l][n];
            float Cv = sC [cur][l][n];
            float dA = __expf(dt * Av);
            h = dA * h + (dt * xv) * Bv;
            float p = h * Cv;
            p = dpp_row_add<0x111>(p);   // row_shr:1
            p = dpp_row_add<0x112>(p);   // row_shr:2
            p = dpp_row_add<0x114>(p);   // row_shr:4
            p = dpp_row_add<0x118>(p);   // row_shr:8  -> lane 15 has row sum
            if (n == 15) {
                float zv = sz[cur][l][c];
                float sig = 1.f / (1.f + __expf(-zv));
                y[(lbase + l) * D_INNER + d] = (p + xv * Dv) * (zv * sig);
            }
        }

        // barrier drains vmcnt (next chunk landed) and retires LDS reads
        asm volatile("s_waitcnt vmcnt(0)" ::: "memory");
        __syncthreads();
        cur ^= 1;
    }
}

// ---------------------------------------------------------------- GEMM  C = A(MxK,f32) * B(NxK,f32)^T, bf16 MFMA compute
// Requires M%128==0, K%32==0. 128x128 tile, 4 waves, 4x4 of 16x16x32 bf16 MFMA.
#define BM 128
#define BN 128
#define BK 32

enum { MODE_PLAIN = 0, MODE_ADD = 1 };

template <int MODE>
__global__ __launch_bounds__(256) void gemm_bt(
    const float* __restrict__ A, const float* __restrict__ B,
    float* Cout, int M, int N, int K, int lda,
    const float* addend)
{
    __shared__ unsigned short As[BM][BK + 8];
    __shared__ unsigned short Bs[BN][BK + 8];

    int tid = threadIdx.x;
    int lane = tid & 63, wv = tid >> 6;
    int wm = (wv >> 1) * 64, wn = (wv & 1) * 64;
    int lm = lane & 15, quad = lane >> 4;
    int m0 = blockIdx.x * BM, n0 = blockIdx.y * BN;

    int r = tid >> 1;            // staging row 0..127
    int ch = (tid & 1) * 16;     // staging col offset 0/16

    float4v acc[4][4] = {};

    for (int k0 = 0; k0 < K; k0 += BK) {
        // ---- stage A (f32 -> bf16), always in-bounds: M%128==0, K%32==0
        {
            const float4v* ap4 = (const float4v*)(A + (size_t)(m0 + r) * lda + k0 + ch);
            float4v f0 = ap4[0], f1 = ap4[1], f2 = ap4[2], f3 = ap4[3];
            short8 t0, t1;
            #pragma unroll
            for (int j = 0; j < 4; ++j) {
                t0[j]     = (short)f2bf(f0[j]);
                t0[j + 4] = (short)f2bf(f1[j]);
                t1[j]     = (short)f2bf(f2[j]);
                t1[j + 4] = (short)f2bf(f3[j]);
            }
            *(short8*)&As[r][ch]     = t0;
            *(short8*)&As[r][ch + 8] = t1;
        }
        // ---- stage B (f32 -> bf16), row guard only
        {
            short8 u0, u1;
            if ((n0 + r) < N) {
                const float4v* bp4 = (const float4v*)(B + (size_t)(n0 + r) * K + k0 + ch);
                float4v g0 = bp4[0], g1 = bp4[1], g2 = bp4[2], g3 = bp4[3];
                #pragma unroll
                for (int j = 0; j < 4; ++j) {
                    u0[j]     = (short)f2bf(g0[j]);
                    u0[j + 4] = (short)f2bf(g1[j]);
                    u1[j]     = (short)f2bf(g2[j]);
                    u1[j + 4] = (short)f2bf(g3[j]);
                }
            } else {
                u0 = (short8)(short)0;
                u1 = (short8)(short)0;
            }
            *(short8*)&Bs[r][ch]     = u0;
            *(short8*)&Bs[r][ch + 8] = u1;
        }
        __syncthreads();

        short8 af[4], bfr[4];
        #pragma unroll
        for (int i = 0; i < 4; ++i)
            af[i] = *(const short8*)&As[wm + i * 16 + lm][quad * 8];
        #pragma unroll
        for (int i = 0; i < 4; ++i)
            bfr[i] = *(const short8*)&Bs[wn + i * 16 + lm][quad * 8];

        #pragma unroll
        for (int mi = 0; mi < 4; ++mi)
            #pragma unroll
            for (int ni = 0; ni < 4; ++ni)
                acc[mi][ni] = __builtin_amdgcn_mfma_f32_16x16x32_bf16(
                    af[mi], bfr[ni], acc[mi][ni], 0, 0, 0);

        __syncthreads();
    }

    // ---- epilogue: C row = quad*4+e, col = lm  (verified C/D layout)
    #pragma unroll
    for (int mi = 0; mi < 4; ++mi) {
        #pragma unroll
        for (int ni = 0; ni < 4; ++ni) {
            int m = m0 + wm + mi * 16 + quad * 4;
            int n = n0 + wn + ni * 16 + lm;
            if (n >= N) continue;
            #pragma unroll
            for (int e = 0; e < 4; ++e) {
                float v = acc[mi][ni][e];
                size_t off = (size_t)(m + e) * N + n;
                if (MODE == MODE_PLAIN) {
                    Cout[off] = v;
                } else {
                    Cout[off] = v + addend[off];
                }
            }
        }
    }
}

// ---------------------------------------------------------------- launch
extern "C" void kernel_launch(void* const* d_in, const int* in_sizes, int n_in,
                              void* d_out, int out_size, void* d_ws, size_t ws_size,
                              hipStream_t stream)
{
    const int*   ids   = (const int*)d_in[0];
    const float* emb   = (const float*)d_in[1];
    const float* ln_w  = (const float*)d_in[2];
    const float* ln_b  = (const float*)d_in[3];
    const float* inw   = (const float*)d_in[4];
    const float* cw    = (const float*)d_in[5];
    const float* cb    = (const float*)d_in[6];
    const float* xpw   = (const float*)d_in[7];
    const float* dtpw  = (const float*)d_in[8];
    const float* dtpb  = (const float*)d_in[9];
    const float* alog  = (const float*)d_in[10];
    const float* Dw    = (const float*)d_in[11];
    const float* outw  = (const float*)d_in[12];
    const float* lnfw  = (const float*)d_in[13];
    const float* lnfb  = (const float*)d_in[14];

    float* ws    = (float*)d_ws;
    float* ha    = ws;                           // 1024*768
    float* hb    = ha    + SEQ * D_MODEL;        // 1024*768
    float* hn    = hb    + SEQ * D_MODEL;        // 1024*768
    float* xz    = hn    + SEQ * D_MODEL;        // 1024*3072
    float* xconv = xz    + SEQ * 2 * D_INNER;    // 1024*1536
    float* xdbl  = xconv + SEQ * D_INNER;        // 1024*80
    float* dtb   = xdbl  + SEQ * 80;             // 1024*1536
    float* y     = dtb   + SEQ * D_INNER;        // 1024*1536

    embed_kernel<<<dim3(3, SEQ), 256, 0, stream>>>(ids, emb, ha);

    float* hcur = ha;
    float* hnxt = hb;
    for (int i = 0; i < 4; ++i) {
        ln_kernel<<<SEQ, 256, 0, stream>>>(hcur, ln_w + i * D_MODEL, ln_b + i * D_MODEL, hn);

        gemm_bt<MODE_PLAIN><<<dim3(8, 24), 256, 0, stream>>>(
            hn, inw + (size_t)i * 2 * D_INNER * D_MODEL, xz,
            SEQ, 2 * D_INNER, D_MODEL, D_MODEL, nullptr);

        conv_silu_kernel<<<dim3(6, SEQ), 256, 0, stream>>>(
            xz, cw + (size_t)i * D_INNER * 4, cb + (size_t)i * D_INNER, xconv);

        gemm_bt<MODE_PLAIN><<<dim3(8, 1), 256, 0, stream>>>(
            xconv, xpw + (size_t)i * 80 * D_INNER, xdbl,
            SEQ, 80, D_INNER, D_INNER, nullptr);

        dtproj_kernel<<<dim3(6, SEQ), 256, 0, stream>>>(
            xdbl, dtpw + (size_t)i * D_INNER * DT_RANK, dtpb + (size_t)i * D_INNER, dtb);

        scan_kernel<<<D_INNER / 16, 256, 0, stream>>>(
            xconv, dtb, xdbl, xz,
            alog + (size_t)i * D_INNER * D_STATE, Dw + (size_t)i * D_INNER, y);

        gemm_bt<MODE_ADD><<<dim3(8, 6), 256, 0, stream>>>(
            y, outw + (size_t)i * D_MODEL * D_INNER, hnxt,
            SEQ, D_MODEL, D_INNER, D_INNER, hcur);

        float* t = hcur; hcur = hnxt; hnxt = t;
    }

    ln_kernel<<<SEQ, 256, 0, stream>>>(hcur, lnfw, lnfb, hn);

    gemm_bt<MODE_PLAIN><<<dim3(8, (VOCAB + BN - 1) / BN), 256, 0, stream>>>(
        hn, emb, (float*)d_out, SEQ, VOCAB, D_MODEL, D_MODEL, nullptr);
}